// Round 11
// baseline (82.496 us; speedup 1.0000x reference)
//
#include <hip/hip_runtime.h>
#include <math.h>

#define NN 2048
#define EE 65536
#define FF 7
#define SS 32
#define LL 16
#define BKT 64     // bucket slots per node, compile-time unrolled gather
#define OCAP 4096  // overflow capacity for deg > 64 (expected 0, correctness guard)
#define NBLK 256   // grid size (1 block per CU, co-resident)

struct Params {
    const float *x; const int *ei;
    const float *W_in, *b_in, *W_msg, *b_msg, *W_ih, *W_hh, *b_ih, *b_hh;
    const float *W_mu, *b_mu, *W_ls, *b_ls, *W_d1, *b_d1;
    float *msg0, *msg1, *msg2, *Abuf, *Bbuf;
    int *cnt, *ocnt, *olist, *bucket, *flags, *go, *seq;
    float *out_mu, *out_ls;
};

__device__ __forceinline__ float fsig(float x) { return 1.f / (1.f + __expf(-x)); }
__device__ __forceinline__ float ftanh(float x) { return 1.f - 2.f / (__expf(2.f * x) + 1.f); }

// agent-scope (LLC coherence point) relaxed ops — cross-XCD visible, no fence,
// no DRAM round-trip, bypass per-XCD L2 staleness.
__device__ __forceinline__ void stwt(float* p, float v) {
    __hip_atomic_store(p, v, __ATOMIC_RELAXED, __HIP_MEMORY_SCOPE_AGENT);
}
__device__ __forceinline__ void stwt_i(int* p, int v) {
    __hip_atomic_store(p, v, __ATOMIC_RELAXED, __HIP_MEMORY_SCOPE_AGENT);
}
__device__ __forceinline__ int ldsys(const int* p) {
    return __hip_atomic_load(p, __ATOMIC_RELAXED, __HIP_MEMORY_SCOPE_AGENT);
}

// Two-hop fence-free grid barrier (used ONCE: after bucket fill + msg0).
__device__ __forceinline__ void gbar(int* flags, int* go, int phase) {
    __syncthreads();   // all waves drained (waitcnt vmcnt(0) before s_barrier)
    if (blockIdx.x == 0) {
        if (threadIdx.x < 64) {
            if (threadIdx.x == 0) stwt_i(flags + 0, phase);
            int l = threadIdx.x;
            for (;;) {
                int a = ldsys(flags + l);
                int b = ldsys(flags + l + 64);
                int c = ldsys(flags + l + 128);
                int d = ldsys(flags + l + 192);
                if (__all(a >= phase && b >= phase && c >= phase && d >= phase)) break;
                __builtin_amdgcn_s_sleep(2);
            }
            if (threadIdx.x == 0) stwt_i(go, phase);
        }
    } else if (threadIdx.x == 0) {
        stwt_i(flags + blockIdx.x, phase);
        while (ldsys(go) < phase) __builtin_amdgcn_s_sleep(8);
    }
    __syncthreads();
}

// Wait until all of this wave's gather sources have published round r.
// Lane s needs bucket slots s (i0) and 32+s (i1) of its node (masked by deg).
__device__ __forceinline__ void wait_ready(const int* seq, int i0, int i1,
                                           int deg, int s, int r) {
    bool need0 = s < deg;
    bool need1 = (SS + s) < deg;
    int j0 = need0 ? i0 : 0;   // invalid slot -> poll seq[0] but ignore result
    int j1 = need1 ? i1 : 0;
    for (;;) {
        bool ok0 = !need0 || (ldsys(&seq[j0]) >= r);
        bool ok1 = !need1 || (ldsys(&seq[j1]) >= r);
        if (__all(ok0 && ok1)) break;
        __builtin_amdgcn_s_sleep(1);
    }
    asm volatile("" ::: "memory");   // don't hoist gather loads above the poll
}

// padded-64 unrolled gather (masked by deg, PLAIN cacheable loads) + GRU.
// pollRnd>0: overflow srcs (not covered by wait_ready) are polled here.
__device__ __forceinline__ float gather_gru(int s, int deg, int i0, int i1,
        const int* ocnt, const int* olist, const int* seq, int pollRnd, int n,
        const float* msg_in, float h0,
        const float* Wih, const float* Whh,
        const float* bih, const float* bhh) {
    float acc = 0.f;
#pragma unroll
    for (int k = 0; k < 32; k++) {
        int bsrc = __shfl(i0, k, 32);
        int src = (k < deg) ? bsrc : 0;          // clamp to valid row
        float v = msg_in[src * SS + s];
        acc += (k < deg) ? v : 0.f;              // mask value
    }
#pragma unroll
    for (int k = 0; k < 32; k++) {
        int kk = 32 + k;
        int bsrc = __shfl(i1, k, 32);
        int src = (kk < deg) ? bsrc : 0;
        float v = msg_in[src * SS + s];
        acc += (kk < deg) ? v : 0.f;
    }
    if (deg > BKT) {                              // correctness guard, expected never
        int oc = ldsys(ocnt); if (oc > OCAP) oc = OCAP;
        for (int i = 0; i < oc; i++)
            if (ldsys(&olist[2 * i + 1]) == n) {
                int src = ldsys(&olist[2 * i]);
                if (pollRnd > 0)
                    while (ldsys(&seq[src]) < pollRnd) __builtin_amdgcn_s_sleep(1);
                acc += msg_in[src * SS + s];
            }
    }
    float xr = bih[s], xz = bih[SS + s], xn = bih[2 * SS + s];
    float hr = bhh[s], hz = bhh[SS + s], hn = bhh[2 * SS + s];
#pragma unroll
    for (int k = 0; k < SS; k++) {
        float av = __shfl(acc, k, 32);
        float hv = __shfl(h0, k, 32);
        const float* wi = Wih + k * 3 * SS;
        const float* wh = Whh + k * 3 * SS;
        xr += av * wi[s];
        xz += av * wi[SS + s];
        xn += av * wi[2 * SS + s];
        hr += hv * wh[s];
        hz += hv * wh[SS + s];
        hn += hv * wh[2 * SS + s];
    }
    float rg = fsig(xr + hr);
    float zg = fsig(xz + hz);
    float ng = ftanh(xn + rg * hn);
    return h0 + (1.f - zg) * ng + zg * h0;
}

// Fused GNN: 256 blocks x 256 threads (1 block/CU), ONE grid barrier +
// per-node dataflow sync (seq ready-counters). Hidden state in VGPR.
__global__ void __launch_bounds__(256) gnn(Params p) {
    int tid = threadIdx.x;
    int gid = blockIdx.x * 256 + tid;
    int n = gid >> 5, s = gid & 31;

    float stc;   // GRU hidden state for (n,s) — only ever used by this thread

    // ---- Phase 0: bucket fill (gid covers EE exactly) + encoder + msg0 ----
    {
        int src = p.ei[gid], dst = p.ei[EE + gid];
        int slot = atomicAdd(&p.cnt[dst], 1);
        if (slot < BKT) stwt_i(&p.bucket[dst * BKT + slot], src);
        else {
            int oi = atomicAdd(p.ocnt, 1);
            if (oi < OCAP) { stwt_i(&p.olist[2 * oi], src); stwt_i(&p.olist[2 * oi + 1], dst); }
        }
        const float* xr = p.x + n * FF;
        float acc = p.b_in[s];
#pragma unroll
        for (int k = 0; k < FF; k++) acc += xr[k] * p.W_in[k * SS + s];
        stc = fmaxf(acc, 0.f);
        float m = p.b_msg[s];
#pragma unroll
        for (int k = 0; k < SS; k++) m += __shfl(stc, k, 32) * p.W_msg[k * SS + s];
        stwt(&p.msg0[n * SS + s], fmaxf(m, 0.f));
    }
    gbar(p.flags, p.go, 1);   // buckets + msg0 globally complete

    // degree + this lane's 2 bucket slots. Bucket contents differ per replay
    // (atomic slot race) -> read LLC-fresh, never a stale L2 line.
    int deg = p.cnt[n];
    int i0 = ldsys(&p.bucket[n * BKT + s]);
    int i1 = ldsys(&p.bucket[n * BKT + SS + s]);

    // ---- Round 0 (msg0 ready by barrier) -> publish msg1, seq=1 ----
    {
        stc = gather_gru(s, deg, i0, i1, p.ocnt, p.olist, p.seq, 0, n, p.msg0, stc,
                         p.W_ih, p.W_hh, p.b_ih, p.b_hh);
        const float* Wm = p.W_msg + 1 * SS * SS;
        const float* bm = p.b_msg + 1 * SS;
        float mv = bm[s];
#pragma unroll
        for (int k = 0; k < SS; k++) mv += __shfl(stc, k, 32) * Wm[k * SS + s];
        stwt(&p.msg1[n * SS + s], fmaxf(mv, 0.f));
        asm volatile("s_waitcnt vmcnt(0)" ::: "memory");   // row at LLC before flag
        if (s == 0) stwt_i(&p.seq[n], 1);
    }

    // ---- Round 1 (poll sources >=1) -> publish msg2, seq=2 ----
    {
        wait_ready(p.seq, i0, i1, deg, s, 1);
        stc = gather_gru(s, deg, i0, i1, p.ocnt, p.olist, p.seq, 1, n, p.msg1, stc,
                         p.W_ih + SS * 3 * SS, p.W_hh + SS * 3 * SS,
                         p.b_ih + 3 * SS, p.b_hh + 3 * SS);
        const float* Wm = p.W_msg + 2 * SS * SS;
        const float* bm = p.b_msg + 2 * SS;
        float mv = bm[s];
#pragma unroll
        for (int k = 0; k < SS; k++) mv += __shfl(stc, k, 32) * Wm[k * SS + s];
        stwt(&p.msg2[n * SS + s], fmaxf(mv, 0.f));
        asm volatile("s_waitcnt vmcnt(0)" ::: "memory");
        if (s == 0) stwt_i(&p.seq[n], 2);
    }

    // ---- Round 2 (poll sources >=2) + heads + decoder operands ----
    {
        wait_ready(p.seq, i0, i1, deg, s, 2);
        stc = gather_gru(s, deg, i0, i1, p.ocnt, p.olist, p.seq, 2, n, p.msg2, stc,
                         p.W_ih + 2 * SS * 3 * SS, p.W_hh + 2 * SS * 3 * SS,
                         p.b_ih + 2 * 3 * SS, p.b_hh + 2 * 3 * SS);
        int l = s & 15;
        const float* W = (s < 16) ? p.W_mu : p.W_ls;
        float v = (s < 16) ? p.b_mu[l] : p.b_ls[l];
#pragma unroll
        for (int k = 0; k < SS; k++) v += __shfl(stc, k, 32) * W[k * LL + l];
        if (s < 16) p.out_mu[n * LL + l] = v; else p.out_ls[n * LL + l] = v;
        // A' = mu@W_d1[:L]+b_d1 (lanes 0-15), B = mu@W_d1[L:] (lanes 16-31);
        // mu row lives in lanes 0..15 so shfl k<16 is valid for all lanes.
        // A/B consumed by the NEXT dispatch -> kernel boundary handles coherence.
        const float* Wd = p.W_d1 + ((s < 16) ? 0 : LL * LL);
        float ab = (s < 16) ? p.b_d1[l] : 0.f;
#pragma unroll
        for (int k = 0; k < LL; k++) ab += __shfl(v, k, 32) * Wd[k * LL + l];
        if (s < 16) p.Abuf[n * LL + l] = ab; else p.Bbuf[n * LL + l] = ab;
    }
}

// Triangular-tiled decoder: 64x64 (bi,bj) tile with bi<=bj, computes symmetric
// prob once per unordered pair, writes tile + transpose (via LDS, coalesced).
__global__ __launch_bounds__(256) void dec_kernel(const float* __restrict__ Abuf,
                                                  const float* __restrict__ Bbuf,
                                                  const float* __restrict__ W_d2,
                                                  const float* __restrict__ b_d2,
                                                  float* __restrict__ out) {
    __shared__ float ldsAj[LL * 64];
    __shared__ float ldsBj[LL * 64];
    __shared__ float ldsT[64 * 65];
    int t = blockIdx.x;
    int bi = (int)((65.f - sqrtf(4225.f - 8.f * (float)t)) * 0.5f);
    if (bi < 0) bi = 0;
    if (bi > 31) bi = 31;
    while (bi > 0 && (65 * bi - bi * bi) / 2 > t) bi--;
    while (bi < 31 && (65 * (bi + 1) - (bi + 1) * (bi + 1)) / 2 <= t) bi++;
    int bj = bi + (t - (65 * bi - bi * bi) / 2);
    int i0 = bi * 64, j0 = bj * 64;
    int tid = threadIdx.x;

    {   // stage j-side rows transposed into LDS (coalesced global float4 loads)
        int jr = tid >> 2, q = tid & 3;
        float4 va = ((const float4*)(Abuf + (size_t)(j0 + jr) * LL))[q];
        float4 vb = ((const float4*)(Bbuf + (size_t)(j0 + jr) * LL))[q];
        int l4 = q * 4;
        ldsAj[(l4 + 0) * 64 + jr] = va.x; ldsAj[(l4 + 1) * 64 + jr] = va.y;
        ldsAj[(l4 + 2) * 64 + jr] = va.z; ldsAj[(l4 + 3) * 64 + jr] = va.w;
        ldsBj[(l4 + 0) * 64 + jr] = vb.x; ldsBj[(l4 + 1) * 64 + jr] = vb.y;
        ldsBj[(l4 + 2) * 64 + jr] = vb.z; ldsBj[(l4 + 3) * 64 + jr] = vb.w;
    }
    __syncthreads();

    int jo = tid & 63;   // j lane
    int ig = tid >> 6;   // i sub-group 0..3
    float aj[LL], bjr[LL], w[LL];
#pragma unroll
    for (int l = 0; l < LL; l++) {
        aj[l] = ldsAj[l * 64 + jo];
        bjr[l] = ldsBj[l * 64 + jo];
        w[l] = W_d2[l];
    }
    float bd2 = b_d2[0];
    int j = j0 + jo;

#pragma unroll 2
    for (int ii = 0; ii < 16; ii++) {
        int i = i0 + ig * 16 + ii;
        const float4* Ai4 = (const float4*)(Abuf + (size_t)i * LL);
        const float4* Bi4 = (const float4*)(Bbuf + (size_t)i * LL);
        float4 a0 = Ai4[0], a1 = Ai4[1], a2 = Ai4[2], a3 = Ai4[3];
        float4 b0 = Bi4[0], b1 = Bi4[1], b2 = Bi4[2], b3 = Bi4[3];
        float ai[LL] = {a0.x, a0.y, a0.z, a0.w, a1.x, a1.y, a1.z, a1.w,
                        a2.x, a2.y, a2.z, a2.w, a3.x, a3.y, a3.z, a3.w};
        float bi_[LL] = {b0.x, b0.y, b0.z, b0.w, b1.x, b1.y, b1.z, b1.w,
                         b2.x, b2.y, b2.z, b2.w, b3.x, b3.y, b3.z, b3.w};
        float accij = 0.f, accji = 0.f;
#pragma unroll
        for (int l = 0; l < LL; l++) {
            accij += w[l] * fmaxf(ai[l] + bjr[l], 0.f);
            accji += w[l] * fmaxf(aj[l] + bi_[l], 0.f);
        }
        float logit = 0.5f * (accij + accji) + bd2;
        float p = 1.f / (1.f + __expf(-logit));
        out[(size_t)i * NN + j] = p;
        ldsT[jo * 65 + ig * 16 + ii] = p;
    }

    if (bi != bj) {  // transposed tile write via LDS (coalesced)
        __syncthreads();
        int jj = tid >> 2, qi = tid & 3;
        float v[16];
#pragma unroll
        for (int m = 0; m < 16; m++) v[m] = ldsT[jj * 65 + qi * 16 + m];
        float4* dst = (float4*)(out + (size_t)(j0 + jj) * NN + i0 + qi * 16);
#pragma unroll
        for (int q4 = 0; q4 < 4; q4++)
            dst[q4] = make_float4(v[4 * q4], v[4 * q4 + 1], v[4 * q4 + 2], v[4 * q4 + 3]);
    }
}

extern "C" void kernel_launch(void* const* d_in, const int* in_sizes, int n_in,
                              void* d_out, int out_size, void* d_ws, size_t ws_size,
                              hipStream_t stream) {
    Params p;
    p.x     = (const float*)d_in[0];
    p.ei    = (const int*)d_in[1];
    p.W_in  = (const float*)d_in[2];
    p.b_in  = (const float*)d_in[3];
    p.W_msg = (const float*)d_in[4];
    p.b_msg = (const float*)d_in[5];
    p.W_ih  = (const float*)d_in[6];
    p.W_hh  = (const float*)d_in[7];
    p.b_ih  = (const float*)d_in[8];
    p.b_hh  = (const float*)d_in[9];
    p.W_mu  = (const float*)d_in[10];
    p.b_mu  = (const float*)d_in[11];
    p.W_ls  = (const float*)d_in[12];
    p.b_ls  = (const float*)d_in[13];
    p.W_d1  = (const float*)d_in[14];
    p.b_d1  = (const float*)d_in[15];
    const float* W_d2 = (const float*)d_in[16];
    const float* b_d2 = (const float*)d_in[17];

    float* ws = (float*)d_ws;
    p.msg0 = ws;                        // N*S  (128B-aligned rows)
    p.msg1 = p.msg0 + NN * SS;          // N*S
    p.msg2 = p.msg1 + NN * SS;          // N*S
    p.Abuf = p.msg2 + NN * SS;          // N*L
    p.Bbuf = p.Abuf + NN * LL;          // N*L
    p.cnt  = (int*)(p.Bbuf + NN * LL);  // N      (memset region start)
    p.ocnt = p.cnt + NN;                // 1
    p.flags = p.ocnt + 1;               // NBLK
    p.go   = p.flags + NBLK;            // 4
    p.seq  = p.go + 4;                  // N      (memset region end)
    p.olist = p.seq + NN;               // 2*OCAP
    p.bucket = p.olist + 2 * OCAP;      // N*BKT

    float* out_adj = (float*)d_out;
    p.out_mu  = out_adj + (size_t)NN * NN;
    p.out_ls  = p.out_mu + NN * LL;

    // zero cnt + ocnt + flags + go + seq (one small memset, graph-capturable)
    hipMemsetAsync(p.cnt, 0, (NN + 1 + NBLK + 4 + NN) * sizeof(int), stream);

    gnn<<<NBLK, 256, 0, stream>>>(p);

    dec_kernel<<<528, 256, 0, stream>>>(p.Abuf, p.Bbuf, W_d2, b_d2, out_adj);
}

// Round 12
// 60.810 us; speedup vs baseline: 1.3566x; 1.3566x over previous
//
#include <hip/hip_runtime.h>
#include <math.h>

#define NN 2048
#define EE 65536
#define FF 7
#define SS 32
#define LL 16
#define BKT 64     // bucket slots per node, compile-time unrolled gather
#define OCAP 4096  // overflow capacity for deg > 64 (expected 0, correctness guard)
#define NBLK 256   // grid size (1 block per CU, co-resident)

struct Params {
    const float *x; const int *ei;
    const float *W_in, *b_in, *W_msg, *b_msg, *W_ih, *W_hh, *b_ih, *b_hh;
    const float *W_mu, *b_mu, *W_ls, *b_ls, *W_d1, *b_d1;
    float *msg0, *msg1, *msg2, *Abuf, *Bbuf;
    int *cnt, *ocnt, *olist, *bucket, *flags, *go;
    float *out_mu, *out_ls;
};

__device__ __forceinline__ float fsig(float x) { return 1.f / (1.f + __expf(-x)); }
__device__ __forceinline__ float ftanh(float x) { return 1.f - 2.f / (__expf(2.f * x) + 1.f); }

// DATA publishes: AGENT scope — coherence point is the LLC (cross-XCD correct,
// no DRAM round-trip). Readers use plain cacheable loads (values are
// deterministic per dispatch, so replay-stale L2 lines are bit-identical).
__device__ __forceinline__ void stwt(float* p, float v) {
    __hip_atomic_store(p, v, __ATOMIC_RELAXED, __HIP_MEMORY_SCOPE_AGENT);
}
__device__ __forceinline__ void stwt_i(int* p, int v) {
    __hip_atomic_store(p, v, __ATOMIC_RELAXED, __HIP_MEMORY_SCOPE_AGENT);
}
__device__ __forceinline__ int ldag(const int* p) {   // uncached (LLC-fresh) read
    return __hip_atomic_load(p, __ATOMIC_RELAXED, __HIP_MEMORY_SCOPE_AGENT);
}
// BARRIER words: SYSTEM scope — unchanged from R9 (measured fastest barrier).
__device__ __forceinline__ void flag_st(int* p, int v) {
    __hip_atomic_store(p, v, __ATOMIC_RELAXED, __HIP_MEMORY_SCOPE_SYSTEM);
}
__device__ __forceinline__ int flag_ld(const int* p) {
    return __hip_atomic_load(p, __ATOMIC_RELAXED, __HIP_MEMORY_SCOPE_SYSTEM);
}

// Two-hop fence-free grid barrier (identical to R9):
//   arrive: each block's leader stores flags[bid]=phase   (no contention)
//   block 0 wave 0 sweeps all 256 flags, sets go; others poll go with backoff.
// Data correctness: cross-block data written via stwt (at LLC) and drained by
// the __syncthreads() vmcnt(0) before the flag store.
__device__ __forceinline__ void gbar(int* flags, int* go, int phase) {
    __syncthreads();
    if (blockIdx.x == 0) {
        if (threadIdx.x < 64) {
            if (threadIdx.x == 0) flag_st(flags + 0, phase);
            int l = threadIdx.x;
            for (;;) {
                int a = flag_ld(flags + l);
                int b = flag_ld(flags + l + 64);
                int c = flag_ld(flags + l + 128);
                int d = flag_ld(flags + l + 192);
                if (__all(a >= phase && b >= phase && c >= phase && d >= phase)) break;
                __builtin_amdgcn_s_sleep(2);
            }
            if (threadIdx.x == 0) flag_st(go, phase);
        }
    } else if (threadIdx.x == 0) {
        flag_st(flags + blockIdx.x, phase);
        while (flag_ld(go) < phase) __builtin_amdgcn_s_sleep(8);
    }
    __syncthreads();
}

// padded-64 unrolled gather (masked by deg, plain cacheable loads) + GRU;
// hidden state carried in a VGPR by the caller.
__device__ __forceinline__ float gather_gru(int s, int deg, int i0, int i1,
        const int* ocnt, const int* olist, int n,
        const float* msg_in, float h0,
        const float* Wih, const float* Whh,
        const float* bih, const float* bhh) {
    float acc = 0.f;
#pragma unroll
    for (int k = 0; k < 32; k++) {
        int bsrc = __shfl(i0, k, 32);
        int src = (k < deg) ? bsrc : 0;          // clamp to valid row
        float v = msg_in[src * SS + s];
        acc += (k < deg) ? v : 0.f;              // mask value
    }
#pragma unroll
    for (int k = 0; k < 32; k++) {
        int kk = 32 + k;
        int bsrc = __shfl(i1, k, 32);
        int src = (kk < deg) ? bsrc : 0;
        float v = msg_in[src * SS + s];
        acc += (kk < deg) ? v : 0.f;
    }
    if (deg > BKT) {                              // correctness guard, expected never
        int oc = ldag(ocnt); if (oc > OCAP) oc = OCAP;
        for (int i = 0; i < oc; i++)
            if (ldag(&olist[2 * i + 1]) == n) acc += msg_in[ldag(&olist[2 * i]) * SS + s];
    }
    float xr = bih[s], xz = bih[SS + s], xn = bih[2 * SS + s];
    float hr = bhh[s], hz = bhh[SS + s], hn = bhh[2 * SS + s];
#pragma unroll
    for (int k = 0; k < SS; k++) {
        float av = __shfl(acc, k, 32);
        float hv = __shfl(h0, k, 32);
        const float* wi = Wih + k * 3 * SS;
        const float* wh = Whh + k * 3 * SS;
        xr += av * wi[s];
        xz += av * wi[SS + s];
        xn += av * wi[2 * SS + s];
        hr += hv * wh[s];
        hz += hv * wh[SS + s];
        hn += hv * wh[2 * SS + s];
    }
    float rg = fsig(xr + hr);
    float zg = fsig(xz + hz);
    float ng = ftanh(xn + rg * hn);
    return h0 + (1.f - zg) * ng + zg * h0;
}

// Fused GNN: 256 blocks x 256 threads (1 block/CU), 3 two-hop grid barriers.
// 65536 threads = 2048 nodes x 32 lanes = 65536 edges. Hidden state in VGPR.
__global__ void __launch_bounds__(256) gnn(Params p) {
    int tid = threadIdx.x;
    int gid = blockIdx.x * 256 + tid;
    int n = gid >> 5, s = gid & 31;

    float stc;   // GRU hidden state for (n,s) — only ever used by this thread

    // ---- Phase 0: bucket fill (gid covers EE exactly) + encoder + msg0 ----
    {
        int src = p.ei[gid], dst = p.ei[EE + gid];
        int slot = atomicAdd(&p.cnt[dst], 1);
        if (slot < BKT) stwt_i(&p.bucket[dst * BKT + slot], src);
        else {
            int oi = atomicAdd(p.ocnt, 1);
            if (oi < OCAP) { stwt_i(&p.olist[2 * oi], src); stwt_i(&p.olist[2 * oi + 1], dst); }
        }
        const float* xr = p.x + n * FF;
        float acc = p.b_in[s];
#pragma unroll
        for (int k = 0; k < FF; k++) acc += xr[k] * p.W_in[k * SS + s];
        stc = fmaxf(acc, 0.f);
        float m = p.b_msg[s];
#pragma unroll
        for (int k = 0; k < SS; k++) m += __shfl(stc, k, 32) * p.W_msg[k * SS + s];
        stwt(&p.msg0[n * SS + s], fmaxf(m, 0.f));
    }
    gbar(p.flags, p.go, 1);

    // degree + this lane's 2 bucket slots. Bucket contents differ per replay
    // (atomic slot race) -> read LLC-fresh, never a (replay-)stale L2 line.
    int deg = p.cnt[n];          // cnt identical every replay: plain load ok
    int i0 = ldag(&p.bucket[n * BKT + s]);
    int i1 = ldag(&p.bucket[n * BKT + SS + s]);

    // ---- Phase 1: round 0 (msg0 -> msg1) ----
    {
        stc = gather_gru(s, deg, i0, i1, p.ocnt, p.olist, n, p.msg0, stc,
                         p.W_ih, p.W_hh, p.b_ih, p.b_hh);
        const float* Wm = p.W_msg + 1 * SS * SS;
        const float* bm = p.b_msg + 1 * SS;
        float mv = bm[s];
#pragma unroll
        for (int k = 0; k < SS; k++) mv += __shfl(stc, k, 32) * Wm[k * SS + s];
        stwt(&p.msg1[n * SS + s], fmaxf(mv, 0.f));
    }
    gbar(p.flags, p.go, 2);

    // ---- Phase 2: round 1 (msg1 -> msg2) ----
    {
        stc = gather_gru(s, deg, i0, i1, p.ocnt, p.olist, n, p.msg1, stc,
                         p.W_ih + SS * 3 * SS, p.W_hh + SS * 3 * SS,
                         p.b_ih + 3 * SS, p.b_hh + 3 * SS);
        const float* Wm = p.W_msg + 2 * SS * SS;
        const float* bm = p.b_msg + 2 * SS;
        float mv = bm[s];
#pragma unroll
        for (int k = 0; k < SS; k++) mv += __shfl(stc, k, 32) * Wm[k * SS + s];
        stwt(&p.msg2[n * SS + s], fmaxf(mv, 0.f));
    }
    gbar(p.flags, p.go, 3);

    // ---- Phase 3: round 2 + heads + decoder operands ----
    {
        stc = gather_gru(s, deg, i0, i1, p.ocnt, p.olist, n, p.msg2, stc,
                         p.W_ih + 2 * SS * 3 * SS, p.W_hh + 2 * SS * 3 * SS,
                         p.b_ih + 2 * 3 * SS, p.b_hh + 2 * 3 * SS);
        int l = s & 15;
        const float* W = (s < 16) ? p.W_mu : p.W_ls;
        float v = (s < 16) ? p.b_mu[l] : p.b_ls[l];
#pragma unroll
        for (int k = 0; k < SS; k++) v += __shfl(stc, k, 32) * W[k * LL + l];
        if (s < 16) p.out_mu[n * LL + l] = v; else p.out_ls[n * LL + l] = v;
        // A' = mu@W_d1[:L]+b_d1 (lanes 0-15), B = mu@W_d1[L:] (lanes 16-31);
        // mu row lives in lanes 0..15 so shfl k<16 is valid for all lanes.
        // A/B consumed by the NEXT dispatch -> kernel boundary handles coherence.
        const float* Wd = p.W_d1 + ((s < 16) ? 0 : LL * LL);
        float ab = (s < 16) ? p.b_d1[l] : 0.f;
#pragma unroll
        for (int k = 0; k < LL; k++) ab += __shfl(v, k, 32) * Wd[k * LL + l];
        if (s < 16) p.Abuf[n * LL + l] = ab; else p.Bbuf[n * LL + l] = ab;
    }
}

// Triangular-tiled decoder: 64x64 (bi,bj) tile with bi<=bj, computes symmetric
// prob once per unordered pair, writes tile + transpose (via LDS, coalesced).
__global__ __launch_bounds__(256) void dec_kernel(const float* __restrict__ Abuf,
                                                  const float* __restrict__ Bbuf,
                                                  const float* __restrict__ W_d2,
                                                  const float* __restrict__ b_d2,
                                                  float* __restrict__ out) {
    __shared__ float ldsAj[LL * 64];
    __shared__ float ldsBj[LL * 64];
    __shared__ float ldsT[64 * 65];
    int t = blockIdx.x;
    int bi = (int)((65.f - sqrtf(4225.f - 8.f * (float)t)) * 0.5f);
    if (bi < 0) bi = 0;
    if (bi > 31) bi = 31;
    while (bi > 0 && (65 * bi - bi * bi) / 2 > t) bi--;
    while (bi < 31 && (65 * (bi + 1) - (bi + 1) * (bi + 1)) / 2 <= t) bi++;
    int bj = bi + (t - (65 * bi - bi * bi) / 2);
    int i0 = bi * 64, j0 = bj * 64;
    int tid = threadIdx.x;

    {   // stage j-side rows transposed into LDS (coalesced global float4 loads)
        int jr = tid >> 2, q = tid & 3;
        float4 va = ((const float4*)(Abuf + (size_t)(j0 + jr) * LL))[q];
        float4 vb = ((const float4*)(Bbuf + (size_t)(j0 + jr) * LL))[q];
        int l4 = q * 4;
        ldsAj[(l4 + 0) * 64 + jr] = va.x; ldsAj[(l4 + 1) * 64 + jr] = va.y;
        ldsAj[(l4 + 2) * 64 + jr] = va.z; ldsAj[(l4 + 3) * 64 + jr] = va.w;
        ldsBj[(l4 + 0) * 64 + jr] = vb.x; ldsBj[(l4 + 1) * 64 + jr] = vb.y;
        ldsBj[(l4 + 2) * 64 + jr] = vb.z; ldsBj[(l4 + 3) * 64 + jr] = vb.w;
    }
    __syncthreads();

    int jo = tid & 63;   // j lane
    int ig = tid >> 6;   // i sub-group 0..3
    float aj[LL], bjr[LL], w[LL];
#pragma unroll
    for (int l = 0; l < LL; l++) {
        aj[l] = ldsAj[l * 64 + jo];
        bjr[l] = ldsBj[l * 64 + jo];
        w[l] = W_d2[l];
    }
    float bd2 = b_d2[0];
    int j = j0 + jo;

#pragma unroll 2
    for (int ii = 0; ii < 16; ii++) {
        int i = i0 + ig * 16 + ii;
        const float4* Ai4 = (const float4*)(Abuf + (size_t)i * LL);
        const float4* Bi4 = (const float4*)(Bbuf + (size_t)i * LL);
        float4 a0 = Ai4[0], a1 = Ai4[1], a2 = Ai4[2], a3 = Ai4[3];
        float4 b0 = Bi4[0], b1 = Bi4[1], b2 = Bi4[2], b3 = Bi4[3];
        float ai[LL] = {a0.x, a0.y, a0.z, a0.w, a1.x, a1.y, a1.z, a1.w,
                        a2.x, a2.y, a2.z, a2.w, a3.x, a3.y, a3.z, a3.w};
        float bi_[LL] = {b0.x, b0.y, b0.z, b0.w, b1.x, b1.y, b1.z, b1.w,
                         b2.x, b2.y, b2.z, b2.w, b3.x, b3.y, b3.z, b3.w};
        float accij = 0.f, accji = 0.f;
#pragma unroll
        for (int l = 0; l < LL; l++) {
            accij += w[l] * fmaxf(ai[l] + bjr[l], 0.f);
            accji += w[l] * fmaxf(aj[l] + bi_[l], 0.f);
        }
        float logit = 0.5f * (accij + accji) + bd2;
        float p = 1.f / (1.f + __expf(-logit));
        out[(size_t)i * NN + j] = p;
        ldsT[jo * 65 + ig * 16 + ii] = p;
    }

    if (bi != bj) {  // transposed tile write via LDS (coalesced)
        __syncthreads();
        int jj = tid >> 2, qi = tid & 3;
        float v[16];
#pragma unroll
        for (int m = 0; m < 16; m++) v[m] = ldsT[jj * 65 + qi * 16 + m];
        float4* dst = (float4*)(out + (size_t)(j0 + jj) * NN + i0 + qi * 16);
#pragma unroll
        for (int q4 = 0; q4 < 4; q4++)
            dst[q4] = make_float4(v[4 * q4], v[4 * q4 + 1], v[4 * q4 + 2], v[4 * q4 + 3]);
    }
}

extern "C" void kernel_launch(void* const* d_in, const int* in_sizes, int n_in,
                              void* d_out, int out_size, void* d_ws, size_t ws_size,
                              hipStream_t stream) {
    Params p;
    p.x     = (const float*)d_in[0];
    p.ei    = (const int*)d_in[1];
    p.W_in  = (const float*)d_in[2];
    p.b_in  = (const float*)d_in[3];
    p.W_msg = (const float*)d_in[4];
    p.b_msg = (const float*)d_in[5];
    p.W_ih  = (const float*)d_in[6];
    p.W_hh  = (const float*)d_in[7];
    p.b_ih  = (const float*)d_in[8];
    p.b_hh  = (const float*)d_in[9];
    p.W_mu  = (const float*)d_in[10];
    p.b_mu  = (const float*)d_in[11];
    p.W_ls  = (const float*)d_in[12];
    p.b_ls  = (const float*)d_in[13];
    p.W_d1  = (const float*)d_in[14];
    p.b_d1  = (const float*)d_in[15];
    const float* W_d2 = (const float*)d_in[16];
    const float* b_d2 = (const float*)d_in[17];

    float* ws = (float*)d_ws;
    p.msg0 = ws;                        // N*S
    p.msg1 = p.msg0 + NN * SS;          // N*S
    p.msg2 = p.msg1 + NN * SS;          // N*S
    p.Abuf = p.msg2 + NN * SS;          // N*L
    p.Bbuf = p.Abuf + NN * LL;          // N*L
    p.cnt  = (int*)(p.Bbuf + NN * LL);  // N      (memset region start)
    p.ocnt = p.cnt + NN;                // 1
    p.flags = p.ocnt + 1;               // NBLK
    p.go   = p.flags + NBLK;            // 4      (memset region end)
    p.olist = p.go + 4;                 // 2*OCAP
    p.bucket = p.olist + 2 * OCAP;      // N*BKT

    float* out_adj = (float*)d_out;
    p.out_mu  = out_adj + (size_t)NN * NN;
    p.out_ls  = p.out_mu + NN * LL;

    // zero cnt + ocnt + flags + go (one small memset, graph-capturable)
    hipMemsetAsync(p.cnt, 0, (NN + 1 + NBLK + 4) * sizeof(int), stream);

    gnn<<<NBLK, 256, 0, stream>>>(p);

    dec_kernel<<<528, 256, 0, stream>>>(p.Abuf, p.Bbuf, W_d2, b_d2, out_adj);
}